// Round 6
// baseline (147284.143 us; speedup 1.0000x reference)
//
#include <hip/hip_runtime.h>
#include <hip/hip_bf16.h>

#define N_NODES 16384
#define E_EDGESN (16384*32)
#define FEAT 512
#define EMB 256
#define HID 512
#define G4 2048      // 4*HID
#define XDIM 512     // 2*EMB
#define NWG 32       // worker workgroups, all on ONE XCD (32 CUs/XCD)
#define NLAUNCH 256  // pigeonhole: 256 blocks over 8 XCDs -> some XCD gets >=32
#define UPW 16       // hidden units per worker wg (16 units x 32 wgs = 512)
#define BLK 8        // pre prefetch block (steps)

typedef __attribute__((ext_vector_type(8))) short bf16x8;
typedef __attribute__((ext_vector_type(4))) float f32x4;

__device__ __forceinline__ float b2f(unsigned short u) {
  union { unsigned int i; float f; } v; v.i = ((unsigned int)u) << 16; return v.f;
}
__device__ __forceinline__ unsigned short f2b(float f) {
  union { float f; unsigned int i; } v; v.f = f;
  unsigned int x = v.i;
  unsigned int r = (x + 0x7FFFu + ((x >> 16) & 1u)) >> 16;
  return (unsigned short)r;
}
__device__ __forceinline__ float fast_sigmoid(float x) {
  return __builtin_amdgcn_rcpf(1.0f + __expf(-x));
}
__device__ __forceinline__ float fast_tanh(float x) {
  return fmaf(-2.0f, __builtin_amdgcn_rcpf(1.0f + __expf(2.0f * x)), 1.0f);
}

// ---------------- K0: dtype detection (bf16 vs fp32 inputs) ----------------
__global__ __launch_bounds__(256) void k_detect(const unsigned* __restrict__ w,
                                                unsigned* __restrict__ flag) {
  __shared__ int cnt;
  if (threadIdx.x == 0) cnt = 0;
  __syncthreads();
  int hits = 0;
#pragma unroll
  for (int j = 0; j < 4; ++j) {
    unsigned wv = w[threadIdx.x * 4 + j];
    unsigned e = (wv >> 7) & 0xFFu;
    if ((e >= 90u && e <= 126u) || ((wv & 0xFFFFu) == 0u)) hits++;
  }
  atomicAdd(&cnt, hits);
  __syncthreads();
  if (threadIdx.x == 0) *flag = (cnt < 512) ? 1u : 0u;   // 1 = fp32 inputs
}

// ---------------- K1: canonicalize float tensor to bf16 ----------------
__global__ void k_convert(const void* __restrict__ src, unsigned short* __restrict__ dst,
                          int n, const unsigned* __restrict__ flag) {
  int i = blockIdx.x * blockDim.x + threadIdx.x;
  if (i >= n) return;
  if (*flag) dst[i] = f2b(((const float*)src)[i]);
  else       dst[i] = ((const unsigned short*)src)[i];
}

// ---------------- K2: tag histogram scatter ----------------
__global__ void k_hist(const int* __restrict__ nid, const int* __restrict__ ntag,
                       unsigned* __restrict__ hist) {
  int e = blockIdx.x * blockDim.x + threadIdx.x;
  if (e < E_EDGESN)
    atomicAdd(&hist[(size_t)nid[e] * FEAT + ntag[e]], 1u);
}

// ---------------- K3: build x = [node_emb | nb_emb] as bf16 ----------------
__global__ __launch_bounds__(256) void k_build_x(
    const int* __restrict__ tags, const unsigned* __restrict__ hist,
    const unsigned short* __restrict__ Wemb, const unsigned short* __restrict__ bemb,
    unsigned short* __restrict__ x) {
  __shared__ int f_lds[160];
  __shared__ float c_lds[160];
  __shared__ int nlist;
  int n = blockIdx.x, c = threadIdx.x;
  if (c == 0) nlist = 0;
  __syncthreads();
  for (int f = c; f < FEAT; f += 256) {
    unsigned cnt = hist[(size_t)n * FEAT + f];
    if (cnt) {
      int idx = atomicAdd(&nlist, 1);
      if (idx < 160) { f_lds[idx] = f; c_lds[idx] = (float)cnt; }
    }
  }
  __syncthreads();
  int m = nlist; if (m > 160) m = 160;
  float be = b2f(bemb[c]);
  int tg = tags[n];
  x[(size_t)n * XDIM + c] = f2b(b2f(Wemb[(size_t)tg * EMB + c]) + be);
  float acc = be;
  for (int j = 0; j < m; ++j)
    acc += c_lds[j] * b2f(Wemb[(size_t)f_lds[j] * EMB + c]);
  x[(size_t)n * XDIM + EMB + c] = f2b(acc);
}

// ---------------- K4: pre = x @ W_ih^T + b_lstm (MFMA bf16) ----------------
// Output PERMUTED: prep[t][unit*4 + gate]; gate = nn>>9, unit = nn&511.
__global__ __launch_bounds__(256) void k_gemm_pre(
    const unsigned short* __restrict__ x, const unsigned short* __restrict__ Wih,
    const unsigned short* __restrict__ blstm, unsigned short* __restrict__ pre) {
  int wave = threadIdx.x >> 6, lane = threadIdx.x & 63;
  int row = lane & 15, quad = lane >> 4;
  int mband = blockIdx.y * 64 + wave * 16;
  int nbase = blockIdx.x * 128;
  f32x4 acc[8] = {};
  const unsigned short* ap = x + (size_t)(mband + row) * XDIM + quad * 8;
  const unsigned short* bp0 = Wih + (size_t)(nbase + row) * XDIM + quad * 8;
  for (int kc = 0; kc < 16; ++kc) {
    bf16x8 af = *(const bf16x8*)(ap + kc * 32);
#pragma unroll
    for (int nt = 0; nt < 8; ++nt) {
      bf16x8 bf = *(const bf16x8*)(bp0 + (size_t)nt * 16 * XDIM + kc * 32);
      acc[nt] = __builtin_amdgcn_mfma_f32_16x16x32_bf16(af, bf, acc[nt], 0, 0, 0);
    }
  }
#pragma unroll
  for (int nt = 0; nt < 8; ++nt) {
    int nn = nbase + nt * 16 + row;
    float bv = b2f(blstm[nn]);
    int pn = ((nn & 511) << 2) | (nn >> 9);   // unit*4 + gate
#pragma unroll
    for (int i = 0; i < 4; ++i) {
      int mm = mband + quad * 4 + i;
      pre[(size_t)mm * G4 + pn] = f2b(acc[nt][i] + bv);
    }
  }
}

// ---------------- K5: XCD-local persistent LSTM scan (v6) ----------------
// 32 worker wgs x 256 thr (1 wave/SIMD), elected on ONE XCD. 16-lane group
// owns one unit (4 gate rows, 128 fp32 weights in VGPRs).
// h exchange, tag-in-data (16 data bits | 16-bit step tag per word):
//   producer: plain store -> FAST mailbox (write-through L1 -> shared XCD L2)
//             + relaxed agent atomic store -> SAFE mailbox (proven r3 path).
//   consumer: [fence(acquire,agent) = buffer_inv, kills stale L1; plain load
//             -> L2 hit] x24; on failure, agent-atomic poll of SAFE mailbox.
//             Cumulative-failure latch -> permanent safe path. Never hangs.
// Ring safety (2 slots, tier-independent): wg writes step t+2 only after it
// read all of t+1; every chunk of t+1 was written only after its owner read
// all of t => slot t&1 is fully consumed before overwrite.
__global__ __launch_bounds__(256, 1) void k_scan(
    const unsigned short* __restrict__ Whh, const unsigned short* __restrict__ prep,
    unsigned* __restrict__ hwF, unsigned* __restrict__ hwS,
    float* __restrict__ embed, int* __restrict__ elect) {
  __shared__ float h_lds[HID];
  __shared__ int rank_s;
  int tid = threadIdx.x;

  if (tid == 0) {
    unsigned xcd;
    asm volatile("s_getreg_b32 %0, hwreg(HW_REG_XCC_ID)" : "=s"(xcd));
    xcd &= 7u;
    int idx = atomicAdd(&elect[xcd], 1);
    int rank = -1;
    if (idx < NWG) {
      if (idx == NWG - 1) atomicCAS(&elect[8], -1, (int)xcd);
      int w;
      while ((w = __hip_atomic_load(&elect[8], __ATOMIC_RELAXED,
                                    __HIP_MEMORY_SCOPE_AGENT)) == -1)
        __builtin_amdgcn_s_sleep(8);
      if (w == (int)xcd) rank = idx;
    }
    rank_s = rank;
  }
  __syncthreads();
  int wg = rank_s;
  if (wg < 0) return;

  int ug = tid >> 4;           // unit within wg [0,16)
  int s  = tid & 15;           // k-slice
  int unit = wg * UPW + ug;    // global unit [0,512)

  // W_hh rows for this unit's 4 gates, k interleaved: k = 32j + 2s + {0,1}
  float wreg[4][32];
#pragma unroll
  for (int g = 0; g < 4; ++g) {
    const unsigned* wp = (const unsigned*)(Whh + (size_t)(g * HID + unit) * HID);
#pragma unroll
    for (int j = 0; j < 16; ++j) {
      unsigned wv = wp[16 * j + s];        // elements 32j+2s, 32j+2s+1
      wreg[g][2 * j]     = b2f((unsigned short)(wv & 0xFFFFu));
      wreg[g][2 * j + 1] = b2f((unsigned short)(wv >> 16));
    }
  }

  ushort4 pcblk[BLK];
  if (s == 0) {
#pragma unroll
    for (int i = 0; i < BLK; ++i)
      pcblk[i] = *(const ushort4*)(prep + (size_t)i * G4 + (unsigned)unit * 4u);
  }

  float cstate = 0.0f, eacc = 0.0f;
  h_lds[tid] = 0.0f;
  h_lds[256 + tid] = 0.0f;
  __syncthreads();

  unsigned long long fB = (unsigned long long)hwF;
  unsigned long long sB = (unsigned long long)hwS;
  int pollslow = 0;
  int failacc = 0;

  for (int tb = 0; tb < N_NODES; tb += BLK) {
#pragma unroll
    for (int p = 0; p < BLK; ++p) {
      int t = tb + p;
      // ---- matvec over h(t-1): conflict-free float2, 4-way broadcast ----
      float a0 = 0.f, a1 = 0.f, a2 = 0.f, a3 = 0.f;
      const float2* hb = (const float2*)h_lds;
#pragma unroll
      for (int j = 0; j < 16; ++j) {
        float2 hv = hb[j * 16 + s];
        a0 += wreg[0][2*j] * hv.x + wreg[0][2*j+1] * hv.y;
        a1 += wreg[1][2*j] * hv.x + wreg[1][2*j+1] * hv.y;
        a2 += wreg[2][2*j] * hv.x + wreg[2][2*j+1] * hv.y;
        a3 += wreg[3][2*j] * hv.x + wreg[3][2*j+1] * hv.y;
      }
#pragma unroll
      for (int off = 1; off < 16; off <<= 1) {
        a0 += __shfl_xor(a0, off);
        a1 += __shfl_xor(a1, off);
        a2 += __shfl_xor(a2, off);
        a3 += __shfl_xor(a3, off);
      }

      unsigned tagw = (unsigned)t & 0xFFFFu;
      unsigned slotoff = (unsigned)((t & 1) << 12);

      if (s == 0) {
        float gi = fast_sigmoid(a0 + b2f(pcblk[p].x));
        float gf = fast_sigmoid(a1 + b2f(pcblk[p].y));
        float gg = fast_tanh   (a2 + b2f(pcblk[p].z));
        float go = fast_sigmoid(a3 + b2f(pcblk[p].w));
        cstate = gf * cstate + gi * gg;
        float hn = go * fast_tanh(cstate);
        eacc += hn;
        if (t < N_NODES - 1) {
          union { float f; unsigned u; } cu; cu.f = hn;
          unsigned long long sv =
              (((unsigned long long)((cu.u << 16) | tagw)) << 32) |
              (unsigned long long)((cu.u & 0xFFFF0000u) | tagw);
          unsigned long long saF = fB + slotoff + (unsigned)unit * 8u;
          asm volatile("global_store_dwordx2 %0, %1, off"
                       :: "v"(saF), "v"(sv) : "memory");
          __hip_atomic_store((unsigned long long*)(uintptr_t)(sB + slotoff + (unsigned)unit * 8u),
                             sv, __ATOMIC_RELAXED, __HIP_MEMORY_SCOPE_AGENT);
        }
        if (p == BLK - 1) {   // prefetch next pre block (consumed steps tb+BLK..)
#pragma unroll
          for (int i = 0; i < BLK; ++i) {
            int row = tb + BLK + i;
            if (row >= N_NODES) row = 0;
            pcblk[i] = *(const ushort4*)(prep + (size_t)row * G4 + (unsigned)unit * 4u);
          }
        }
      }

      if (t < N_NODES - 1) {
        unsigned long long pa = fB + slotoff + (unsigned)tid * 16u;
        unsigned long long qa = sB + slotoff + (unsigned)tid * 16u;
        unsigned v0, v1, v2, v3;
        int got = 0;
        if (!pollslow) {
          int tries = 0;
          while (tries < 24) {
            __builtin_amdgcn_fence(__ATOMIC_ACQUIRE, "agent");   // buffer_inv: drop stale L1
            unsigned long long a, b;
            asm volatile("global_load_dwordx2 %0, %2, off\n\t"
                         "global_load_dwordx2 %1, %3, off\n\t"
                         "s_waitcnt vmcnt(0)"
                         : "=v"(a), "=v"(b) : "v"(pa), "v"(pa + 8u) : "memory");
            v0 = (unsigned)a; v1 = (unsigned)(a >> 32);
            v2 = (unsigned)b; v3 = (unsigned)(b >> 32);
            if ((((v0 ^ tagw) | (v1 ^ tagw) | (v2 ^ tagw) | (v3 ^ tagw)) & 0xFFFFu) == 0u) {
              got = 1; break;
            }
            ++tries;
          }
          failacc += tries;
          if (failacc > 8192) pollslow = 1;
        }
        if (!got) {   // memory-model-correct path (r3-proven): cannot hang
          unsigned long long* q0 = (unsigned long long*)(uintptr_t)qa;
          unsigned long long* q1 = (unsigned long long*)(uintptr_t)(qa + 8u);
          for (;;) {
            unsigned long long a = __hip_atomic_load(q0, __ATOMIC_RELAXED, __HIP_MEMORY_SCOPE_AGENT);
            unsigned long long b = __hip_atomic_load(q1, __ATOMIC_RELAXED, __HIP_MEMORY_SCOPE_AGENT);
            v0 = (unsigned)a; v1 = (unsigned)(a >> 32);
            v2 = (unsigned)b; v3 = (unsigned)(b >> 32);
            if ((((v0 ^ tagw) | (v1 ^ tagw) | (v2 ^ tagw) | (v3 ^ tagw)) & 0xFFFFu) == 0u) break;
            __builtin_amdgcn_s_sleep(1);
          }
        }
        union { unsigned u; float f; } r0, r1;
        r0.u = (v0 & 0xFFFF0000u) | (v1 >> 16);
        r1.u = (v2 & 0xFFFF0000u) | (v3 >> 16);
        h_lds[2 * tid]     = r0.f;
        h_lds[2 * tid + 1] = r1.f;
        __syncthreads();
      }
    }
  }
  if (s == 0) embed[unit] = eacc;
}

// ---------------- K6: MLP head + log_softmax ----------------
__global__ __launch_bounds__(512) void k_head(
    const float* __restrict__ embed, const unsigned short* __restrict__ W1,
    const unsigned short* __restrict__ b1, const unsigned short* __restrict__ W2,
    const unsigned short* __restrict__ b2, void* __restrict__ out,
    const unsigned* __restrict__ flag) {
  __shared__ float e_s[HID], h1_s[HID];
  __shared__ float lg[16];
  int tid = threadIdx.x;
  e_s[tid] = embed[tid];
  __syncthreads();
  float sum = b2f(b1[tid]);
  for (int i = 0; i < HID; ++i)
    sum += e_s[i] * b2f(W1[(size_t)i * HID + tid]);
  h1_s[tid] = fmaxf(sum, 0.0f);
  __syncthreads();
  if (tid < 10) {
    float l = b2f(b2[tid]);
    for (int j = 0; j < HID; ++j)
      l += h1_s[j] * b2f(W2[(size_t)j * 10 + tid]);
    lg[tid] = l;
  }
  __syncthreads();
  if (tid == 0) {
    float m = -1e30f;
    for (int c = 0; c < 10; ++c) m = fmaxf(m, lg[c]);
    float se = 0.f;
    for (int c = 0; c < 10; ++c) se += expf(lg[c] - m);
    float lse = m + logf(se);
    if (*flag) {
      for (int c = 0; c < 10; ++c) ((float*)out)[c] = lg[c] - lse;
    } else {
      for (int c = 0; c < 10; ++c) ((unsigned short*)out)[c] = f2b(lg[c] - lse);
    }
  }
}

extern "C" void kernel_launch(void* const* d_in, const int* in_sizes, int n_in,
                              void* d_out, int out_size, void* d_ws, size_t ws_size,
                              hipStream_t stream) {
  const int* node_tags = (const int*)d_in[0];
  const int* nid = (const int*)d_in[1];
  const int* ntag = (const int*)d_in[2];
  // d_in[3] = label, unused

  char* ws = (char*)d_ws;
  unsigned short* pre  = (unsigned short*)ws;                     // 67,108,864
  unsigned short* x    = (unsigned short*)(ws + 67108864);        // 16,777,216
  unsigned*       hist = (unsigned*)(ws + 83886080);              // 33,554,432
  char* tail = ws + 117440512;
  unsigned* hwF   = (unsigned*)tail;                              // 8192 B fast mailbox (NOT zeroed: poison tag 0xAAAA never matches t<0x4000)
  unsigned* hwS   = (unsigned*)(tail + 8192);                     // 8192 B safe mailbox
  unsigned* flag  = (unsigned*)(tail + 16384);
  float*    embed = (float*)(tail + 16448);                       // 2048 B
  int*      elect = (int*)(tail + 18496);                         // 64 B
  char* wc = tail + 20480;                                        // bf16 weight copies
  unsigned short* Wemb_c  = (unsigned short*)(wc);
  unsigned short* bemb_c  = (unsigned short*)(wc + 262144);
  unsigned short* Wih_c   = (unsigned short*)(wc + 262656);
  unsigned short* Whh_c   = (unsigned short*)(wc + 2359808);
  unsigned short* blstm_c = (unsigned short*)(wc + 4456960);
  unsigned short* W1_c    = (unsigned short*)(wc + 4461056);
  unsigned short* b1_c    = (unsigned short*)(wc + 4985344);
  unsigned short* W2_c    = (unsigned short*)(wc + 4986368);
  unsigned short* b2_c    = (unsigned short*)(wc + 4996608);

  hipMemsetAsync(hist, 0, 33554432, stream);       // hist must start at zero
  hipMemsetAsync(elect, 0, 32, stream);            // per-XCD counters = 0
  hipMemsetAsync(elect + 8, 0xFF, 4, stream);      // winner = -1

  k_detect<<<1, 256, 0, stream>>>((const unsigned*)d_in[6], flag);

  struct { const void* s; unsigned short* d; int n; } cv[9] = {
    { d_in[4],  Wemb_c,  FEAT * EMB },
    { d_in[5],  bemb_c,  EMB },
    { d_in[6],  Wih_c,   G4 * XDIM },
    { d_in[7],  Whh_c,   G4 * HID },
    { d_in[8],  blstm_c, G4 },
    { d_in[9],  W1_c,    HID * HID },
    { d_in[10], b1_c,    HID },
    { d_in[11], W2_c,    HID * 10 },
    { d_in[12], b2_c,    10 },
  };
  for (int i = 0; i < 9; ++i)
    k_convert<<<(cv[i].n + 255) / 256, 256, 0, stream>>>(cv[i].s, cv[i].d, cv[i].n, flag);

  k_hist<<<E_EDGESN / 256, 256, 0, stream>>>(nid, ntag, hist);
  k_build_x<<<N_NODES, 256, 0, stream>>>(node_tags, hist, Wemb_c, bemb_c, x);
  k_gemm_pre<<<dim3(G4 / 128, N_NODES / 64), 256, 0, stream>>>(x, Wih_c, blstm_c, pre);
  k_scan<<<NLAUNCH, 256, 0, stream>>>(Whh_c, pre, hwF, hwS, embed, elect);
  k_head<<<1, 512, 0, stream>>>(embed, W1_c, b1_c, W2_c, b2_c, d_out, flag);
}

// Round 7
// 32635.468 us; speedup vs baseline: 4.5130x; 4.5130x over previous
//
#include <hip/hip_runtime.h>
#include <hip/hip_bf16.h>

#define N_NODES 16384
#define E_EDGESN (16384*32)
#define FEAT 512
#define EMB 256
#define HID 512
#define G4 2048      // 4*HID
#define XDIM 512     // 2*EMB
#define NWG 32       // worker workgroups, all on ONE XCD (32 CUs/XCD)
#define NLAUNCH 256  // pigeonhole: 256 blocks over 8 XCDs -> some XCD gets >=32
#define UPW 16       // hidden units per worker wg (16 units x 32 wgs = 512)
#define BLK 8        // pre prefetch block (steps)

typedef __attribute__((ext_vector_type(8))) short bf16x8;
typedef __attribute__((ext_vector_type(4))) float f32x4;

__device__ __forceinline__ float b2f(unsigned short u) {
  union { unsigned int i; float f; } v; v.i = ((unsigned int)u) << 16; return v.f;
}
__device__ __forceinline__ unsigned short f2b(float f) {
  union { float f; unsigned int i; } v; v.f = f;
  unsigned int x = v.i;
  unsigned int r = (x + 0x7FFFu + ((x >> 16) & 1u)) >> 16;
  return (unsigned short)r;
}
__device__ __forceinline__ float fast_sigmoid(float x) {
  return __builtin_amdgcn_rcpf(1.0f + __expf(-x));
}
__device__ __forceinline__ float fast_tanh(float x) {
  return fmaf(-2.0f, __builtin_amdgcn_rcpf(1.0f + __expf(2.0f * x)), 1.0f);
}

// ---------------- K0: dtype detection (bf16 vs fp32 inputs) ----------------
__global__ __launch_bounds__(256) void k_detect(const unsigned* __restrict__ w,
                                                unsigned* __restrict__ flag) {
  __shared__ int cnt;
  if (threadIdx.x == 0) cnt = 0;
  __syncthreads();
  int hits = 0;
#pragma unroll
  for (int j = 0; j < 4; ++j) {
    unsigned wv = w[threadIdx.x * 4 + j];
    unsigned e = (wv >> 7) & 0xFFu;
    if ((e >= 90u && e <= 126u) || ((wv & 0xFFFFu) == 0u)) hits++;
  }
  atomicAdd(&cnt, hits);
  __syncthreads();
  if (threadIdx.x == 0) *flag = (cnt < 512) ? 1u : 0u;   // 1 = fp32 inputs
}

// ---------------- K1: canonicalize float tensor to bf16 ----------------
__global__ void k_convert(const void* __restrict__ src, unsigned short* __restrict__ dst,
                          int n, const unsigned* __restrict__ flag) {
  int i = blockIdx.x * blockDim.x + threadIdx.x;
  if (i >= n) return;
  if (*flag) dst[i] = f2b(((const float*)src)[i]);
  else       dst[i] = ((const unsigned short*)src)[i];
}

// ---------------- K2: tag histogram scatter ----------------
__global__ void k_hist(const int* __restrict__ nid, const int* __restrict__ ntag,
                       unsigned* __restrict__ hist) {
  int e = blockIdx.x * blockDim.x + threadIdx.x;
  if (e < E_EDGESN)
    atomicAdd(&hist[(size_t)nid[e] * FEAT + ntag[e]], 1u);
}

// ---------------- K3: build x = [node_emb | nb_emb] as bf16 ----------------
__global__ __launch_bounds__(256) void k_build_x(
    const int* __restrict__ tags, const unsigned* __restrict__ hist,
    const unsigned short* __restrict__ Wemb, const unsigned short* __restrict__ bemb,
    unsigned short* __restrict__ x) {
  __shared__ int f_lds[160];
  __shared__ float c_lds[160];
  __shared__ int nlist;
  int n = blockIdx.x, c = threadIdx.x;
  if (c == 0) nlist = 0;
  __syncthreads();
  for (int f = c; f < FEAT; f += 256) {
    unsigned cnt = hist[(size_t)n * FEAT + f];
    if (cnt) {
      int idx = atomicAdd(&nlist, 1);
      if (idx < 160) { f_lds[idx] = f; c_lds[idx] = (float)cnt; }
    }
  }
  __syncthreads();
  int m = nlist; if (m > 160) m = 160;
  float be = b2f(bemb[c]);
  int tg = tags[n];
  x[(size_t)n * XDIM + c] = f2b(b2f(Wemb[(size_t)tg * EMB + c]) + be);
  float acc = be;
  for (int j = 0; j < m; ++j)
    acc += c_lds[j] * b2f(Wemb[(size_t)f_lds[j] * EMB + c]);
  x[(size_t)n * XDIM + EMB + c] = f2b(acc);
}

// ---------------- K4: pre = x @ W_ih^T + b_lstm (MFMA bf16) ----------------
// Output PERMUTED: prep[t][unit*4 + gate]; gate = nn>>9, unit = nn&511.
__global__ __launch_bounds__(256) void k_gemm_pre(
    const unsigned short* __restrict__ x, const unsigned short* __restrict__ Wih,
    const unsigned short* __restrict__ blstm, unsigned short* __restrict__ pre) {
  int wave = threadIdx.x >> 6, lane = threadIdx.x & 63;
  int row = lane & 15, quad = lane >> 4;
  int mband = blockIdx.y * 64 + wave * 16;
  int nbase = blockIdx.x * 128;
  f32x4 acc[8] = {};
  const unsigned short* ap = x + (size_t)(mband + row) * XDIM + quad * 8;
  const unsigned short* bp0 = Wih + (size_t)(nbase + row) * XDIM + quad * 8;
  for (int kc = 0; kc < 16; ++kc) {
    bf16x8 af = *(const bf16x8*)(ap + kc * 32);
#pragma unroll
    for (int nt = 0; nt < 8; ++nt) {
      bf16x8 bf = *(const bf16x8*)(bp0 + (size_t)nt * 16 * XDIM + kc * 32);
      acc[nt] = __builtin_amdgcn_mfma_f32_16x16x32_bf16(af, bf, acc[nt], 0, 0, 0);
    }
  }
#pragma unroll
  for (int nt = 0; nt < 8; ++nt) {
    int nn = nbase + nt * 16 + row;
    float bv = b2f(blstm[nn]);
    int pn = ((nn & 511) << 2) | (nn >> 9);   // unit*4 + gate
#pragma unroll
    for (int i = 0; i < 4; ++i) {
      int mm = mband + quad * 4 + i;
      pre[(size_t)mm * G4 + pn] = f2b(acc[nt][i] + bv);
    }
  }
}

// ---------------- K5: XCD-local persistent LSTM scan (v7) ----------------
// 32 worker wgs x 256 thr (1 wave/SIMD), elected on ONE XCD.
// h exchange, tag-in-data (16 data bits | 16-bit step tag per word):
//   producer: PLAIN store -> FAST mailbox. L1 is write-through -> the only
//     durable copy is the SHARED per-XCD L2, which the store updates.
//     Plus relaxed agent-atomic store -> SAFE mailbox (r3-proven LLC path).
//   consumer: up to 64 un-fenced `sc0` loads (bypass own L1, serviced by the
//     shared L2; NO fence -> no L2 invalidation). If a step fully fails,
//     fall to agent-atomic poll of SAFE mailbox; after 12 fully-failed steps
//     latch permanently onto the safe path. Never hangs; worst case = r3.
// Ring safety (2 slots, tier-independent): a wg writes step t+2 only after
// reading all of t+1; each chunk of t+1 was written only after its owner read
// all of t => slot t&1 fully consumed before overwrite.
__global__ __launch_bounds__(256, 1) void k_scan(
    const unsigned short* __restrict__ Whh, const unsigned short* __restrict__ prep,
    unsigned* __restrict__ hwF, unsigned* __restrict__ hwS,
    float* __restrict__ embed, int* __restrict__ elect) {
  __shared__ float h_lds[HID];
  __shared__ int rank_s;
  int tid = threadIdx.x;

  if (tid == 0) {
    unsigned xcd;
    asm volatile("s_getreg_b32 %0, hwreg(HW_REG_XCC_ID)" : "=s"(xcd));
    xcd &= 7u;
    int idx = atomicAdd(&elect[xcd], 1);
    int rank = -1;
    if (idx < NWG) {
      if (idx == NWG - 1) atomicCAS(&elect[8], -1, (int)xcd);
      int w;
      while ((w = __hip_atomic_load(&elect[8], __ATOMIC_RELAXED,
                                    __HIP_MEMORY_SCOPE_AGENT)) == -1)
        __builtin_amdgcn_s_sleep(8);
      if (w == (int)xcd) rank = idx;
    }
    rank_s = rank;
  }
  __syncthreads();
  int wg = rank_s;
  if (wg < 0) return;

  int ug = tid >> 4;           // unit within wg [0,16)
  int s  = tid & 15;           // k-slice
  int unit = wg * UPW + ug;    // global unit [0,512)

  // W_hh rows for this unit's 4 gates, k interleaved: k = 32j + 2s + {0,1}
  float wreg[4][32];
#pragma unroll
  for (int g = 0; g < 4; ++g) {
    const unsigned* wp = (const unsigned*)(Whh + (size_t)(g * HID + unit) * HID);
#pragma unroll
    for (int j = 0; j < 16; ++j) {
      unsigned wv = wp[16 * j + s];        // elements 32j+2s, 32j+2s+1
      wreg[g][2 * j]     = b2f((unsigned short)(wv & 0xFFFFu));
      wreg[g][2 * j + 1] = b2f((unsigned short)(wv >> 16));
    }
  }

  ushort4 pcblk[BLK];
  if (s == 0) {
#pragma unroll
    for (int i = 0; i < BLK; ++i)
      pcblk[i] = *(const ushort4*)(prep + (size_t)i * G4 + (unsigned)unit * 4u);
  }

  float cstate = 0.0f, eacc = 0.0f;
  h_lds[tid] = 0.0f;
  h_lds[256 + tid] = 0.0f;
  __syncthreads();

  unsigned long long fB = (unsigned long long)hwF;
  unsigned long long sB = (unsigned long long)hwS;
  int pollslow = 0;    // latched: fast path abandoned
  int stepfails = 0;   // steps where all fast tries failed

  for (int tb = 0; tb < N_NODES; tb += BLK) {
#pragma unroll
    for (int p = 0; p < BLK; ++p) {
      int t = tb + p;
      // ---- matvec over h(t-1): conflict-free float2, 4-way broadcast ----
      float a0 = 0.f, a1 = 0.f, a2 = 0.f, a3 = 0.f;
      const float2* hb = (const float2*)h_lds;
#pragma unroll
      for (int j = 0; j < 16; ++j) {
        float2 hv = hb[j * 16 + s];
        a0 += wreg[0][2*j] * hv.x + wreg[0][2*j+1] * hv.y;
        a1 += wreg[1][2*j] * hv.x + wreg[1][2*j+1] * hv.y;
        a2 += wreg[2][2*j] * hv.x + wreg[2][2*j+1] * hv.y;
        a3 += wreg[3][2*j] * hv.x + wreg[3][2*j+1] * hv.y;
      }
#pragma unroll
      for (int off = 1; off < 16; off <<= 1) {
        a0 += __shfl_xor(a0, off);
        a1 += __shfl_xor(a1, off);
        a2 += __shfl_xor(a2, off);
        a3 += __shfl_xor(a3, off);
      }

      unsigned tagw = (unsigned)t & 0xFFFFu;
      unsigned slotoff = (unsigned)((t & 1) << 12);

      if (s == 0) {
        float gi = fast_sigmoid(a0 + b2f(pcblk[p].x));
        float gf = fast_sigmoid(a1 + b2f(pcblk[p].y));
        float gg = fast_tanh   (a2 + b2f(pcblk[p].z));
        float go = fast_sigmoid(a3 + b2f(pcblk[p].w));
        cstate = gf * cstate + gi * gg;
        float hn = go * fast_tanh(cstate);
        eacc += hn;
        if (t < N_NODES - 1) {
          union { float f; unsigned u; } cu; cu.f = hn;
          unsigned long long sv =
              (((unsigned long long)((cu.u << 16) | tagw)) << 32) |
              (unsigned long long)((cu.u & 0xFFFF0000u) | tagw);
          unsigned long long saF = fB + slotoff + (unsigned)unit * 8u;
          // plain write-back store: lands in the SHARED per-XCD L2
          asm volatile("global_store_dwordx2 %0, %1, off"
                       :: "v"(saF), "v"(sv) : "memory");
          // safe duplicate through the LLC coherence point (r3-proven)
          __hip_atomic_store((unsigned long long*)(uintptr_t)(sB + slotoff + (unsigned)unit * 8u),
                             sv, __ATOMIC_RELAXED, __HIP_MEMORY_SCOPE_AGENT);
        }
        if (p == BLK - 1) {   // prefetch next pre block (fire-and-forget)
#pragma unroll
          for (int i = 0; i < BLK; ++i) {
            int row = tb + BLK + i;
            if (row >= N_NODES) row = 0;
            pcblk[i] = *(const ushort4*)(prep + (size_t)row * G4 + (unsigned)unit * 4u);
          }
        }
      }

      if (t < N_NODES - 1) {
        unsigned long long pa = fB + slotoff + (unsigned)tid * 16u;
        unsigned long long qa = sB + slotoff + (unsigned)tid * 16u;
        unsigned v0, v1, v2, v3;
        int got = 0;
        if (!pollslow) {
          for (int tries = 0; tries < 64; ++tries) {
            unsigned long long a, b;
            // sc0: bypass own L1, serviced by shared XCD L2. NO fence.
            asm volatile("global_load_dwordx2 %0, %2, off sc0\n\t"
                         "global_load_dwordx2 %1, %3, off sc0\n\t"
                         "s_waitcnt vmcnt(0)"
                         : "=v"(a), "=v"(b) : "v"(pa), "v"(pa + 8u) : "memory");
            v0 = (unsigned)a; v1 = (unsigned)(a >> 32);
            v2 = (unsigned)b; v3 = (unsigned)(b >> 32);
            if ((((v0 ^ tagw) | (v1 ^ tagw) | (v2 ^ tagw) | (v3 ^ tagw)) & 0xFFFFu) == 0u) {
              got = 1; break;
            }
          }
          if (!got && ++stepfails >= 12) pollslow = 1;
        }
        if (!got) {   // agent-scope safe path (r3-proven): cannot hang
          unsigned long long* q0 = (unsigned long long*)(uintptr_t)qa;
          unsigned long long* q1 = (unsigned long long*)(uintptr_t)(qa + 8u);
          for (;;) {
            unsigned long long a = __hip_atomic_load(q0, __ATOMIC_RELAXED, __HIP_MEMORY_SCOPE_AGENT);
            unsigned long long b = __hip_atomic_load(q1, __ATOMIC_RELAXED, __HIP_MEMORY_SCOPE_AGENT);
            v0 = (unsigned)a; v1 = (unsigned)(a >> 32);
            v2 = (unsigned)b; v3 = (unsigned)(b >> 32);
            if ((((v0 ^ tagw) | (v1 ^ tagw) | (v2 ^ tagw) | (v3 ^ tagw)) & 0xFFFFu) == 0u) break;
            __builtin_amdgcn_s_sleep(1);
          }
        }
        union { unsigned u; float f; } r0, r1;
        r0.u = (v0 & 0xFFFF0000u) | (v1 >> 16);
        r1.u = (v2 & 0xFFFF0000u) | (v3 >> 16);
        h_lds[2 * tid]     = r0.f;
        h_lds[2 * tid + 1] = r1.f;
        __syncthreads();
      }
    }
  }
  if (s == 0) embed[unit] = eacc;
}

// ---------------- K6: MLP head + log_softmax ----------------
__global__ __launch_bounds__(512) void k_head(
    const float* __restrict__ embed, const unsigned short* __restrict__ W1,
    const unsigned short* __restrict__ b1, const unsigned short* __restrict__ W2,
    const unsigned short* __restrict__ b2, void* __restrict__ out,
    const unsigned* __restrict__ flag) {
  __shared__ float e_s[HID], h1_s[HID];
  __shared__ float lg[16];
  int tid = threadIdx.x;
  e_s[tid] = embed[tid];
  __syncthreads();
  float sum = b2f(b1[tid]);
  for (int i = 0; i < HID; ++i)
    sum += e_s[i] * b2f(W1[(size_t)i * HID + tid]);
  h1_s[tid] = fmaxf(sum, 0.0f);
  __syncthreads();
  if (tid < 10) {
    float l = b2f(b2[tid]);
    for (int j = 0; j < HID; ++j)
      l += h1_s[j] * b2f(W2[(size_t)j * 10 + tid]);
    lg[tid] = l;
  }
  __syncthreads();
  if (tid == 0) {
    float m = -1e30f;
    for (int c = 0; c < 10; ++c) m = fmaxf(m, lg[c]);
    float se = 0.f;
    for (int c = 0; c < 10; ++c) se += expf(lg[c] - m);
    float lse = m + logf(se);
    if (*flag) {
      for (int c = 0; c < 10; ++c) ((float*)out)[c] = lg[c] - lse;
    } else {
      for (int c = 0; c < 10; ++c) ((unsigned short*)out)[c] = f2b(lg[c] - lse);
    }
  }
}

extern "C" void kernel_launch(void* const* d_in, const int* in_sizes, int n_in,
                              void* d_out, int out_size, void* d_ws, size_t ws_size,
                              hipStream_t stream) {
  const int* node_tags = (const int*)d_in[0];
  const int* nid = (const int*)d_in[1];
  const int* ntag = (const int*)d_in[2];
  // d_in[3] = label, unused

  char* ws = (char*)d_ws;
  unsigned short* pre  = (unsigned short*)ws;                     // 67,108,864
  unsigned short* x    = (unsigned short*)(ws + 67108864);        // 16,777,216
  unsigned*       hist = (unsigned*)(ws + 83886080);              // 33,554,432
  char* tail = ws + 117440512;
  unsigned* hwF   = (unsigned*)tail;                              // 8192 B fast mailbox (NOT zeroed: poison tag 0xAAAA never matches t<0x4000)
  unsigned* hwS   = (unsigned*)(tail + 8192);                     // 8192 B safe mailbox
  unsigned* flag  = (unsigned*)(tail + 16384);
  float*    embed = (float*)(tail + 16448);                       // 2048 B
  int*      elect = (int*)(tail + 18496);                         // 64 B
  char* wc = tail + 20480;                                        // bf16 weight copies
  unsigned short* Wemb_c  = (unsigned short*)(wc);
  unsigned short* bemb_c  = (unsigned short*)(wc + 262144);
  unsigned short* Wih_c   = (unsigned short*)(wc + 262656);
  unsigned short* Whh_c   = (unsigned short*)(wc + 2359808);
  unsigned short* blstm_c = (unsigned short*)(wc + 4456960);
  unsigned short* W1_c    = (unsigned short*)(wc + 4461056);
  unsigned short* b1_c    = (unsigned short*)(wc + 4985344);
  unsigned short* W2_c    = (unsigned short*)(wc + 4986368);
  unsigned short* b2_c    = (unsigned short*)(wc + 4996608);

  hipMemsetAsync(hist, 0, 33554432, stream);       // hist must start at zero
  hipMemsetAsync(elect, 0, 32, stream);            // per-XCD counters = 0
  hipMemsetAsync(elect + 8, 0xFF, 4, stream);      // winner = -1

  k_detect<<<1, 256, 0, stream>>>((const unsigned*)d_in[6], flag);

  struct { const void* s; unsigned short* d; int n; } cv[9] = {
    { d_in[4],  Wemb_c,  FEAT * EMB },
    { d_in[5],  bemb_c,  EMB },
    { d_in[6],  Wih_c,   G4 * XDIM },
    { d_in[7],  Whh_c,   G4 * HID },
    { d_in[8],  blstm_c, G4 },
    { d_in[9],  W1_c,    HID * HID },
    { d_in[10], b1_c,    HID },
    { d_in[11], W2_c,    HID * 10 },
    { d_in[12], b2_c,    10 },
  };
  for (int i = 0; i < 9; ++i)
    k_convert<<<(cv[i].n + 255) / 256, 256, 0, stream>>>(cv[i].s, cv[i].d, cv[i].n, flag);

  k_hist<<<E_EDGESN / 256, 256, 0, stream>>>(nid, ntag, hist);
  k_build_x<<<N_NODES, 256, 0, stream>>>(node_tags, hist, Wemb_c, bemb_c, x);
  k_gemm_pre<<<dim3(G4 / 128, N_NODES / 64), 256, 0, stream>>>(x, Wih_c, blstm_c, pre);
  k_scan<<<NLAUNCH, 256, 0, stream>>>(Whh_c, pre, hwF, hwS, embed, elect);
  k_head<<<1, 512, 0, stream>>>(embed, W1_c, b1_c, W2_c, b2_c, d_out, flag);
}